// Round 6
// baseline (62.049 us; speedup 1.0000x reference)
//
#include <hip/hip_runtime.h>
#include <hip/hip_bf16.h>
#include <float.h>

#define B 16
#define H 32
#define HKV 8
#define G 4
#define D 128
#define LMAX 2048
#define BATCH 32
#define SCALE 0.08838834764831844f  // 1/sqrt(128)

// Async global->LDS, 16B/lane. LDS dest is wave-uniform base (+lane*16 in HW).
__device__ __forceinline__ void stage16(const float* gsrc, float* lds_base) {
#if __has_builtin(__builtin_amdgcn_global_load_lds)
    __builtin_amdgcn_global_load_lds(
        (const __attribute__((address_space(1))) void*)gsrc,
        (__attribute__((address_space(3))) void*)lds_base, 16, 0, 0);
#else
    const int lane = threadIdx.x & 63;
    *(float4*)((char*)lds_base + lane * 16) = *(const float4*)gsrc;
#endif
}

// Kernel 1: per (b, kv-head, split) flash-decode partial.
// Deep-pipelined LDS staging: 2 buffers, counted s_waitcnt vmcnt(4) (never a
// full drain in the main loop), raw s_barrier. K rows stored with a 16B-chunk
// XOR swizzle (chunk ^ row&7), applied via pre-swizzled GLOBAL source (rule:
// global_load_lds dest must be linear) and the same XOR on the LDS read.
// part_o : [B][HKV][NSPLIT][G][D]  (written only if split non-empty)
// part_ml: [B][HKV][NSPLIT][G][2]  (m, sum_exp; always written)
template <int CHUNK>
__global__ __launch_bounds__(256) void attn_partial(
    const float* __restrict__ q,
    const float* __restrict__ kin,
    const float* __restrict__ vin,
    const float* __restrict__ kc,
    const float* __restrict__ vc,
    const int*  __restrict__ slot_mapping,
    const int*  __restrict__ active_slots,
    const int*  __restrict__ context_lens,
    float* __restrict__ part_o,
    float* __restrict__ part_ml)
{
    constexpr int NSPLIT = LMAX / CHUNK;
    const int tid   = threadIdx.x;
    const int split = blockIdx.x % NSPLIT;
    const int h     = (blockIdx.x / NSPLIT) % HKV;
    const int b     = blockIdx.x / (NSPLIT * HKV);

    const int ctx   = context_lens[b];
    const int start = split * CHUNK;
    int nvalid = ctx - start;
    if (nvalid > CHUNK) nvalid = CHUNK;

    const size_t pbase = ((size_t)(b * HKV + h) * NSPLIT + split) * G;

    if (nvalid <= 0) {
        if (tid < G * 2) part_ml[pbase * 2 + tid] = (tid & 1) ? 0.f : -FLT_MAX;
        return;
    }

    __shared__ float stg[2][BATCH * D];     // 2 x 16KB staged K/V rows (swizzled)
    __shared__ float sc[CHUNK][G];          // scores, then p
    __shared__ const float* kp[CHUNK];
    __shared__ const float* vp[CHUNK];
    __shared__ int sm[16];

    if (tid < 16) sm[tid] = slot_mapping[tid];
    __syncthreads();

    // resolve slot -> row pointers (coalesced)
    for (int li = tid; li < nvalid; li += 256) {
        const int s = active_slots[b * LMAX + start + li];
        int ov = -1;
#pragma unroll
        for (int j = 0; j < 16; ++j)
            if (sm[j] == s) ov = j;
        kp[li] = (ov >= 0) ? kin + ((size_t)ov * HKV + h) * D : kc + ((size_t)s * HKV + h) * D;
        vp[li] = (ov >= 0) ? vin + ((size_t)ov * HKV + h) * D : vc + ((size_t)s * HKV + h) * D;
    }

    const int grp   = tid >> 3;   // 0..31 : QK row
    const int lane8 = tid & 7;
    const int wv    = tid >> 6;   // wave 0..3
    const int lane  = tid & 63;
    const int grp8  = tid >> 5;   // 0..7 : PV row-group
    const int dl    = tid & 31;   // PV d-chunk

    // q fragments (pre-scaled): qv[g][j] holds d-chunk (j*8 + lane8)
    float4 qv[G][4];
#pragma unroll
    for (int g = 0; g < G; ++g) {
        const float* qp = q + ((size_t)(b * H + h * G + g)) * D;
#pragma unroll
        for (int i = 0; i < 4; ++i) {
            float4 t = *(const float4*)(qp + i * 32 + lane8 * 4);
            qv[g][i] = make_float4(t.x * SCALE, t.y * SCALE, t.z * SCALE, t.w * SCALE);
        }
    }
    __syncthreads();   // kp/vp visible; drains all pre-loop VMEM (exact vmcnt from here)

    const int nb = (nvalid + BATCH - 1) / BATCH;
    const int NT = 2 * nb;      // unified stream: K batches 0..nb-1, then V batches

    // stage stream-index st into stg[st&1]: exactly 4 issues per wave, clamped tail
    auto STAGE = [&](int st) {
        const float* const* ptrs = (st < nb) ? kp : vp;
        const int tb = (st < nb) ? st : st - nb;
#pragma unroll
        for (int p = 0; p < 4; ++p) {
            const int r  = wv * 8 + 2 * p + (lane >> 5);    // dest row in batch
            int li = tb * BATCH + r;
            if (li >= nvalid) li = nvalid - 1;              // clamp: uniform issue count
            // source chunk pre-swizzled so LDS slot s holds chunk (s ^ (r&7))
            stage16(ptrs[li] + (((lane & 31) ^ (r & 7)) * 4),
                    &stg[st & 1][(wv * 8 + 2 * p) * D]);
        }
    };

    auto COMPUTE_QK = [&](int t) {
        const int li = t * BATCH + grp;
        if (li < nvalid) {
            const float* kr = &stg[t & 1][grp * D];
            const int sw = grp & 7;
            float pd0 = 0.f, pd1 = 0.f, pd2 = 0.f, pd3 = 0.f;
#pragma unroll
            for (int j = 0; j < 4; ++j) {
                const int slot = (j * 8 + lane8) ^ sw;      // chunk c at LDS slot c^sw
                const float4 kv = *(const float4*)(kr + slot * 4);
                pd0 += kv.x * qv[0][j].x + kv.y * qv[0][j].y + kv.z * qv[0][j].z + kv.w * qv[0][j].w;
                pd1 += kv.x * qv[1][j].x + kv.y * qv[1][j].y + kv.z * qv[1][j].z + kv.w * qv[1][j].w;
                pd2 += kv.x * qv[2][j].x + kv.y * qv[2][j].y + kv.z * qv[2][j].z + kv.w * qv[2][j].w;
                pd3 += kv.x * qv[3][j].x + kv.y * qv[3][j].y + kv.z * qv[3][j].z + kv.w * qv[3][j].w;
            }
#pragma unroll
            for (int msk = 1; msk < 8; msk <<= 1) {
                pd0 += __shfl_xor(pd0, msk, 8);
                pd1 += __shfl_xor(pd1, msk, 8);
                pd2 += __shfl_xor(pd2, msk, 8);
                pd3 += __shfl_xor(pd3, msk, 8);
            }
            if (lane8 == 0)
                *(float4*)&sc[li][0] = make_float4(pd0, pd1, pd2, pd3);
        }
    };

    float4 a0 = {0,0,0,0}, a1 = {0,0,0,0}, a2 = {0,0,0,0}, a3 = {0,0,0,0};
    auto COMPUTE_PV = [&](int tv) {
        const int buf = (nb + tv) & 1;
#pragma unroll
        for (int ii = 0; ii < 4; ++ii) {
            const int r  = ii * 8 + grp8;
            const int li = tv * BATCH + r;
            if (li < nvalid) {
                const float4 vv = *(const float4*)(&stg[buf][r * D + ((dl ^ (r & 7)) * 4)]);
                const float4 p4 = *(const float4*)&sc[li][0];
                a0.x += p4.x * vv.x; a0.y += p4.x * vv.y; a0.z += p4.x * vv.z; a0.w += p4.x * vv.w;
                a1.x += p4.y * vv.x; a1.y += p4.y * vv.y; a1.z += p4.y * vv.z; a1.w += p4.y * vv.w;
                a2.x += p4.z * vv.x; a2.y += p4.z * vv.y; a2.z += p4.z * vv.z; a2.w += p4.z * vv.w;
                a3.x += p4.w * vv.x; a3.y += p4.w * vv.y; a3.z += p4.w * vv.z; a3.w += p4.w * vv.w;
            }
        }
    };

    // ---- deep-pipelined main loop: depth-2, counted vmcnt, raw barriers
    STAGE(0);
    if (NT > 1) STAGE(1);
    for (int t = 0; t < NT; ++t) {
        if (t < NT - 1) asm volatile("s_waitcnt vmcnt(4)" ::: "memory");
        else            asm volatile("s_waitcnt vmcnt(0)" ::: "memory");
        __builtin_amdgcn_s_barrier();       // batch t visible to all waves

        if (t == nb) {
            // softmax: wave g handles head g (V batches already in flight)
            const int g = wv;
            float m = -FLT_MAX;
            for (int i = lane; i < nvalid; i += 64) m = fmaxf(m, sc[i][g]);
#pragma unroll
            for (int msk = 1; msk < 64; msk <<= 1) m = fmaxf(m, __shfl_xor(m, msk, 64));
            float sum = 0.f;
            for (int i = lane; i < nvalid; i += 64) {
                const float p = __expf(sc[i][g] - m);
                sc[i][g] = p;
                sum += p;
            }
#pragma unroll
            for (int msk = 1; msk < 64; msk <<= 1) sum += __shfl_xor(sum, msk, 64);
            if (lane == 0) {
                part_ml[(pbase + g) * 2 + 0] = m;
                part_ml[(pbase + g) * 2 + 1] = sum;
            }
            __builtin_amdgcn_s_barrier();   // p values visible before PV
        }

        if (t < nb) COMPUTE_QK(t);
        else        COMPUTE_PV(t - nb);

        __builtin_amdgcn_s_barrier();       // compute(t) done -> buf reusable
        if (t + 2 < NT) STAGE(t + 2);
    }

    // ---- cross-group PV combine: alias red[8][G][D] onto stg (dead now)
    __syncthreads();
    {
        float* red = &stg[0][0];   // 16KB
        *(float4*)&red[((grp8 * G + 0) * D) + dl * 4] = a0;
        *(float4*)&red[((grp8 * G + 1) * D) + dl * 4] = a1;
        *(float4*)&red[((grp8 * G + 2) * D) + dl * 4] = a2;
        *(float4*)&red[((grp8 * G + 3) * D) + dl * 4] = a3;
        __syncthreads();
#pragma unroll
        for (int k2 = 0; k2 < 2; ++k2) {
            const int o = tid * 2 + k2;     // [G][D] flat
            const int g = o >> 7, d = o & 127;
            float s = 0.f;
#pragma unroll
            for (int r = 0; r < 8; ++r) s += red[(r * G + g) * D + d];
            part_o[(pbase + g) * D + d] = s;
        }
    }
}

// Kernel 2: merge nsplit partials per (b, h, g) with log-sum-exp combine.
__global__ __launch_bounds__(128) void attn_reduce(
    const float* __restrict__ part_o,
    const float* __restrict__ part_ml,
    float* __restrict__ out,
    int nsplit)
{
    const int g = blockIdx.x & 3;
    const int h = (blockIdx.x >> 2) & 7;
    const int b = blockIdx.x >> 5;
    const int d = threadIdx.x;

    __shared__ float mlds[32], llds[32];
    const size_t base = (size_t)(b * HKV + h) * nsplit;

    for (int s = d; s < nsplit; s += 128) {
        mlds[s] = part_ml[((base + s) * G + g) * 2 + 0];
        llds[s] = part_ml[((base + s) * G + g) * 2 + 1];
    }
    __syncthreads();

    float M = -FLT_MAX;
    for (int s = 0; s < nsplit; ++s)
        if (llds[s] > 0.f) M = fmaxf(M, mlds[s]);

    float L = 0.f, acc = 0.f;
    for (int s = 0; s < nsplit; ++s) {
        const float l = llds[s];
        if (l > 0.f) {
            const float e = __expf(mlds[s] - M);
            L += l * e;
            acc += e * part_o[((base + s) * G + g) * D + d];
        }
    }
    out[((size_t)(b * H) + h * G + g) * D + d] = acc / (L > 0.f ? L : 1.f);
}

extern "C" void kernel_launch(void* const* d_in, const int* in_sizes, int n_in,
                              void* d_out, int out_size, void* d_ws, size_t ws_size,
                              hipStream_t stream) {
    const float* q  = (const float*)d_in[0];
    const float* k  = (const float*)d_in[1];
    const float* v  = (const float*)d_in[2];
    const float* kc = (const float*)d_in[3];
    const float* vc = (const float*)d_in[4];
    const int* slot_mapping = (const int*)d_in[5];
    const int* active_slots = (const int*)d_in[6];
    const int* context_lens = (const int*)d_in[7];
    float* out = (float*)d_out;

    const size_t perSplit = (size_t)B * HKV * (G * D + G * 2) * sizeof(float);
    const int nsplit = (ws_size >= 16 * perSplit) ? 16 : 8;

    float* part_o  = (float*)d_ws;
    float* part_ml = part_o + (size_t)B * HKV * nsplit * G * D;

    if (nsplit == 16) {
        attn_partial<128><<<B * HKV * 16, 256, 0, stream>>>(
            q, k, v, kc, vc, slot_mapping, active_slots, context_lens, part_o, part_ml);
    } else {
        attn_partial<256><<<B * HKV * 8, 256, 0, stream>>>(
            q, k, v, kc, vc, slot_mapping, active_slots, context_lens, part_o, part_ml);
    }
    attn_reduce<<<B * HKV * G, 128, 0, stream>>>(part_o, part_ml, out, nsplit);
}

// Round 7
// 45.414 us; speedup vs baseline: 1.3663x; 1.3663x over previous
//
#include <hip/hip_runtime.h>
#include <hip/hip_bf16.h>
#include <float.h>

#define B 16
#define H 32
#define HKV 8
#define G 4
#define D 128
#define LMAX 2048
#define SCALE 0.08838834764831844f  // 1/sqrt(128)

// Async global->LDS, 16B/lane. LDS dest is wave-uniform base (+lane*16 in HW).
__device__ __forceinline__ void stage16(const float* gsrc, float* lds_base) {
#if __has_builtin(__builtin_amdgcn_global_load_lds)
    __builtin_amdgcn_global_load_lds(
        (const __attribute__((address_space(1))) void*)gsrc,
        (__attribute__((address_space(3))) void*)lds_base, 16, 0, 0);
#else
    const int lane = threadIdx.x & 63;
    *(float4*)((char*)lds_base + lane * 16) = *(const float4*)gsrc;
#endif
}

// Kernel 1: per (b, kv-head, split) flash-decode partial.
// BARRIER-FREE hot loops: each wave stages its OWN 8-row K/V batches into its
// OWN 8KB LDS region (2 buffers x 8 rows x 512B), ordered only by that wave's
// s_waitcnt vmcnt(N). Exactly 4 global_load_lds per STAGE (tail rows clamped
// to keep the per-wave vmcnt arithmetic exact). 16B-chunk XOR swizzle
// (chunk ^ row&7) applied via pre-swizzled global source + same XOR on reads.
// part_o : [B][HKV][NSPLIT][G][D]  (written only if split non-empty)
// part_ml: [B][HKV][NSPLIT][G][2]  (m, sum_exp; always written)
template <int CHUNK>
__global__ __launch_bounds__(256) void attn_partial(
    const float* __restrict__ q,
    const float* __restrict__ kin,
    const float* __restrict__ vin,
    const float* __restrict__ kc,
    const float* __restrict__ vc,
    const int*  __restrict__ slot_mapping,
    const int*  __restrict__ active_slots,
    const int*  __restrict__ context_lens,
    float* __restrict__ part_o,
    float* __restrict__ part_ml)
{
    constexpr int NSPLIT = LMAX / CHUNK;
    const int tid   = threadIdx.x;
    const int split = blockIdx.x % NSPLIT;
    const int h     = (blockIdx.x / NSPLIT) % HKV;
    const int b     = blockIdx.x / (NSPLIT * HKV);

    const int ctx   = context_lens[b];
    const int start = split * CHUNK;
    int nvalid = ctx - start;
    if (nvalid > CHUNK) nvalid = CHUNK;

    const size_t pbase = ((size_t)(b * HKV + h) * NSPLIT + split) * G;

    if (nvalid <= 0) {
        if (tid < G * 2) part_ml[pbase * 2 + tid] = (tid & 1) ? 0.f : -FLT_MAX;
        return;
    }

    __shared__ float stg[4][2][8 * D];   // [wave][buf][8 rows] = 32KB total
    __shared__ float4 sc4[CHUNK];        // per-row score float4 (g=0..3)
    __shared__ const float* kp[CHUNK];
    __shared__ const float* vp[CHUNK];
    __shared__ int sm[16];

    float* scf = (float*)&sc4[0];

    if (tid < 16) sm[tid] = slot_mapping[tid];
    __syncthreads();

    // resolve slot -> row pointers (coalesced)
    for (int li = tid; li < nvalid; li += 256) {
        const int s = active_slots[b * LMAX + start + li];
        int ov = -1;
#pragma unroll
        for (int j = 0; j < 16; ++j)
            if (sm[j] == s) ov = j;
        kp[li] = (ov >= 0) ? kin + ((size_t)ov * HKV + h) * D : kc + ((size_t)s * HKV + h) * D;
        vp[li] = (ov >= 0) ? vin + ((size_t)ov * HKV + h) * D : vc + ((size_t)s * HKV + h) * D;
    }

    const int wv    = tid >> 6;   // wave 0..3
    const int lane  = tid & 63;
    const int gr    = lane >> 3;  // 0..7 : wave-local QK row
    const int lane8 = lane & 7;
    const int gr2   = lane >> 5;  // 0..1 : PV row-parity
    const int dl    = lane & 31;  // PV d-chunk
    const int grp8  = tid >> 5;   // 0..7 : epilogue partial index

    // q fragments (pre-scaled): qv[g][j] holds chunk (j*8 + lane8)
    float4 qv[G][4];
#pragma unroll
    for (int g = 0; g < G; ++g) {
        const float* qp = q + ((size_t)(b * H + h * G + g)) * D;
#pragma unroll
        for (int i = 0; i < 4; ++i) {
            float4 t = *(const float4*)(qp + i * 32 + lane8 * 4);
            qv[g][i] = make_float4(t.x * SCALE, t.y * SCALE, t.z * SCALE, t.w * SCALE);
        }
    }
    __syncthreads();   // kp/vp visible; drains ALL prior VMEM -> exact vmcnt from here

    const int nb = (nvalid + 31) >> 5;   // 32-row block-batches; wave owns 8 of each
    const int NT = 2 * nb;               // stream: K batches 0..nb-1, then V batches
    float* stgw = &stg[wv][0][0];

    // stage stream-index st into this wave's buf (st&1): exactly 4 issues
    auto STAGE = [&](int st) {
        const float* const* ptrs = (st < nb) ? kp : vp;
        const int tb = (st < nb) ? st : st - nb;
        float* dst = stgw + (st & 1) * (8 * D);
#pragma unroll
        for (int p = 0; p < 4; ++p) {
            const int rr = 2 * p + (lane >> 5);        // wave-local row 0..7
            int li = tb * 32 + wv * 8 + rr;
            if (li >= nvalid) li = nvalid - 1;         // clamp: uniform issue count
            stage16(ptrs[li] + (((lane & 31) ^ rr) * 4), dst + 2 * p * D);
        }
    };

    auto COMPUTE_QK = [&](int t) {
        const int li = t * 32 + wv * 8 + gr;
        if (li < nvalid) {
            const float* kr = stgw + (t & 1) * (8 * D) + gr * D;
            float pd0 = 0.f, pd1 = 0.f, pd2 = 0.f, pd3 = 0.f;
#pragma unroll
            for (int j = 0; j < 4; ++j) {
                const int slot = (j * 8 + lane8) ^ gr;   // chunk c lives at slot c^row
                const float4 kv = *(const float4*)(kr + slot * 4);
                pd0 += kv.x * qv[0][j].x + kv.y * qv[0][j].y + kv.z * qv[0][j].z + kv.w * qv[0][j].w;
                pd1 += kv.x * qv[1][j].x + kv.y * qv[1][j].y + kv.z * qv[1][j].z + kv.w * qv[1][j].w;
                pd2 += kv.x * qv[2][j].x + kv.y * qv[2][j].y + kv.z * qv[2][j].z + kv.w * qv[2][j].w;
                pd3 += kv.x * qv[3][j].x + kv.y * qv[3][j].y + kv.z * qv[3][j].z + kv.w * qv[3][j].w;
            }
#pragma unroll
            for (int msk = 1; msk < 8; msk <<= 1) {
                pd0 += __shfl_xor(pd0, msk, 8);
                pd1 += __shfl_xor(pd1, msk, 8);
                pd2 += __shfl_xor(pd2, msk, 8);
                pd3 += __shfl_xor(pd3, msk, 8);
            }
            if (lane8 == 0) sc4[li] = make_float4(pd0, pd1, pd2, pd3);
        }
    };

    float4 a0 = {0,0,0,0}, a1 = {0,0,0,0}, a2 = {0,0,0,0}, a3 = {0,0,0,0};
    auto COMPUTE_PV = [&](int tv) {
        const float* vb = stgw + ((nb + tv) & 1) * (8 * D);
#pragma unroll
        for (int ii = 0; ii < 4; ++ii) {
            const int rr = gr2 + 2 * ii;
            const int li = tv * 32 + wv * 8 + rr;
            if (li < nvalid) {
                const float4 vv = *(const float4*)(vb + rr * D + ((dl ^ rr) * 4));
                const float4 p4 = sc4[li];
                a0.x += p4.x * vv.x; a0.y += p4.x * vv.y; a0.z += p4.x * vv.z; a0.w += p4.x * vv.w;
                a1.x += p4.y * vv.x; a1.y += p4.y * vv.y; a1.z += p4.y * vv.z; a1.w += p4.y * vv.w;
                a2.x += p4.z * vv.x; a2.y += p4.z * vv.y; a2.z += p4.z * vv.z; a2.w += p4.z * vv.w;
                a3.x += p4.w * vv.x; a3.y += p4.w * vv.y; a3.z += p4.w * vv.z; a3.w += p4.w * vv.w;
            }
        }
    };

    // ---- K pass: per-wave self-paced, NO barriers
    STAGE(0);
    if (NT > 1) STAGE(1);
    for (int t = 0; t < nb; ++t) {
        asm volatile("s_waitcnt vmcnt(4)" ::: "memory");   // wave's batch t ready
        COMPUTE_QK(t);
        if (t + 2 < NT) STAGE(t + 2);
    }

    // ---- softmax (2 barriers; vmcnt NOT drained -> V prefetch stays in flight)
    asm volatile("s_waitcnt lgkmcnt(0)\ns_barrier" ::: "memory");
    {
        const int g = wv;   // wave g handles head g
        float m = -FLT_MAX;
        for (int i = lane; i < nvalid; i += 64) m = fmaxf(m, scf[i * 4 + g]);
#pragma unroll
        for (int msk = 1; msk < 64; msk <<= 1) m = fmaxf(m, __shfl_xor(m, msk, 64));
        float sum = 0.f;
        for (int i = lane; i < nvalid; i += 64) {
            const float p = __expf(scf[i * 4 + g] - m);
            scf[i * 4 + g] = p;
            sum += p;
        }
#pragma unroll
        for (int msk = 1; msk < 64; msk <<= 1) sum += __shfl_xor(sum, msk, 64);
        if (lane == 0) {
            part_ml[(pbase + g) * 2 + 0] = m;
            part_ml[(pbase + g) * 2 + 1] = sum;
        }
    }
    asm volatile("s_waitcnt lgkmcnt(0)\ns_barrier" ::: "memory");

    // ---- V pass: per-wave self-paced, NO barriers
    for (int tv = 0; tv < nb; ++tv) {
        if (tv < nb - 1) asm volatile("s_waitcnt vmcnt(4)" ::: "memory");
        else             asm volatile("s_waitcnt vmcnt(0)" ::: "memory");
        COMPUTE_PV(tv);
        const int st = nb + tv + 2;
        if (st < NT) STAGE(st);
    }

    // ---- cross-wave PV combine: red[8][G][D] aliases stg (dead; all vmcnt==0)
    __syncthreads();
    {
        float* red = &stg[0][0][0];   // 16KB
        *(float4*)&red[((grp8 * G + 0) * D) + dl * 4] = a0;
        *(float4*)&red[((grp8 * G + 1) * D) + dl * 4] = a1;
        *(float4*)&red[((grp8 * G + 2) * D) + dl * 4] = a2;
        *(float4*)&red[((grp8 * G + 3) * D) + dl * 4] = a3;
        __syncthreads();
#pragma unroll
        for (int k2 = 0; k2 < 2; ++k2) {
            const int o = tid * 2 + k2;     // [G][D] flat
            const int g = o >> 7, d = o & 127;
            float s = 0.f;
#pragma unroll
            for (int r = 0; r < 8; ++r) s += red[(r * G + g) * D + d];
            part_o[(pbase + g) * D + d] = s;
        }
    }
}

// Kernel 2: merge nsplit partials per (b, h, g) with log-sum-exp combine.
__global__ __launch_bounds__(128) void attn_reduce(
    const float* __restrict__ part_o,
    const float* __restrict__ part_ml,
    float* __restrict__ out,
    int nsplit)
{
    const int g = blockIdx.x & 3;
    const int h = (blockIdx.x >> 2) & 7;
    const int b = blockIdx.x >> 5;
    const int d = threadIdx.x;

    __shared__ float mlds[32], llds[32];
    const size_t base = (size_t)(b * HKV + h) * nsplit;

    for (int s = d; s < nsplit; s += 128) {
        mlds[s] = part_ml[((base + s) * G + g) * 2 + 0];
        llds[s] = part_ml[((base + s) * G + g) * 2 + 1];
    }
    __syncthreads();

    float M = -FLT_MAX;
    for (int s = 0; s < nsplit; ++s)
        if (llds[s] > 0.f) M = fmaxf(M, mlds[s]);

    float L = 0.f, acc = 0.f;
    for (int s = 0; s < nsplit; ++s) {
        const float l = llds[s];
        if (l > 0.f) {
            const float e = __expf(mlds[s] - M);
            L += l * e;
            acc += e * part_o[((base + s) * G + g) * D + d];
        }
    }
    out[((size_t)(b * H) + h * G + g) * D + d] = acc / (L > 0.f ? L : 1.f);
}

extern "C" void kernel_launch(void* const* d_in, const int* in_sizes, int n_in,
                              void* d_out, int out_size, void* d_ws, size_t ws_size,
                              hipStream_t stream) {
    const float* q  = (const float*)d_in[0];
    const float* k  = (const float*)d_in[1];
    const float* v  = (const float*)d_in[2];
    const float* kc = (const float*)d_in[3];
    const float* vc = (const float*)d_in[4];
    const int* slot_mapping = (const int*)d_in[5];
    const int* active_slots = (const int*)d_in[6];
    const int* context_lens = (const int*)d_in[7];
    float* out = (float*)d_out;

    const size_t perSplit = (size_t)B * HKV * (G * D + G * 2) * sizeof(float);
    const int nsplit = (ws_size >= 16 * perSplit) ? 16 : 8;

    float* part_o  = (float*)d_ws;
    float* part_ml = part_o + (size_t)B * HKV * nsplit * G * D;

    if (nsplit == 16) {
        attn_partial<128><<<B * HKV * 16, 256, 0, stream>>>(
            q, k, v, kc, vc, slot_mapping, active_slots, context_lens, part_o, part_ml);
    } else {
        attn_partial<256><<<B * HKV * 8, 256, 0, stream>>>(
            q, k, v, kc, vc, slot_mapping, active_slots, context_lens, part_o, part_ml);
    }
    attn_reduce<<<B * HKV * G, 128, 0, stream>>>(part_o, part_ml, out, nsplit);
}

// Round 8
// 41.794 us; speedup vs baseline: 1.4846x; 1.0866x over previous
//
#include <hip/hip_runtime.h>
#include <hip/hip_bf16.h>
#include <float.h>

#define B 16
#define H 32
#define HKV 8
#define G 4
#define D 128
#define LMAX 2048
#define SCALE 0.08838834764831844f  // 1/sqrt(128)

// Kernel 1: ONE WAVE per (b, kv-head, split). No barriers, no inter-wave
// coupling: the wave resolves its chunk's slot pointers, computes QK^T
// (8-lane groups per row), does softmax entirely in-wave (row l owned by
// lane l), then PV (2 row-halves x 32 d-lanes), and stores the partial.
// Invalid rows are handled branchlessly: loads clamp to row nvalid-1 and
// their p is forced to 0, so they contribute nothing.
// part_o : [B][HKV][NSPLIT][G][D]  (written only if split non-empty)
// part_ml: [B][HKV][NSPLIT][G][2]  (m, sum_exp; always written)
template <int CHUNK>
__global__ __launch_bounds__(64, 3) void attn_partial(
    const float* __restrict__ q,
    const float* __restrict__ kin,
    const float* __restrict__ vin,
    const float* __restrict__ kc,
    const float* __restrict__ vc,
    const int*  __restrict__ slot_mapping,
    const int*  __restrict__ active_slots,
    const int*  __restrict__ context_lens,
    float* __restrict__ part_o,
    float* __restrict__ part_ml)
{
    constexpr int NSPLIT = LMAX / CHUNK;
    const int tid   = threadIdx.x;            // 0..63
    const int split = blockIdx.x % NSPLIT;
    const int h     = (blockIdx.x / NSPLIT) % HKV;
    const int b     = blockIdx.x / (NSPLIT * HKV);

    const int ctx   = context_lens[b];
    const int start = split * CHUNK;
    int nvalid = ctx - start;
    if (nvalid > CHUNK) nvalid = CHUNK;

    const size_t pbase = ((size_t)(b * HKV + h) * NSPLIT + split) * G;

    if (nvalid <= 0) {
        if (tid < G * 2) part_ml[pbase * 2 + tid] = (tid & 1) ? 0.f : -FLT_MAX;
        return;
    }

    __shared__ const float* kp[CHUNK];   // wave-private (1 wave per block)
    __shared__ const float* vp[CHUNK];
    __shared__ float4 sc4[CHUNK];        // scores then p, one float4 (4 heads) per row

    // ---- resolve slot -> row pointers (uniform slot_mapping -> scalar loads)
    for (int li = tid; li < nvalid; li += 64) {
        const int s = active_slots[b * LMAX + start + li];
        int ov = -1;
#pragma unroll
        for (int j = 0; j < 16; ++j)
            if (slot_mapping[j] == s) ov = j;
        kp[li] = (ov >= 0) ? kin + ((size_t)ov * HKV + h) * D : kc + ((size_t)s * HKV + h) * D;
        vp[li] = (ov >= 0) ? vin + ((size_t)ov * HKV + h) * D : vc + ((size_t)s * HKV + h) * D;
    }

    // ---- QK^T: 8 groups x 8 lanes; group gr owns rows it*8+gr
    const int grp   = tid >> 3;
    const int lane8 = tid & 7;

    float4 qv[G][4];   // q fragments, pre-scaled: qv[g][i] = chunk (i*8+lane8)
#pragma unroll
    for (int g = 0; g < G; ++g) {
        const float* qp = q + ((size_t)(b * H + h * G + g)) * D;
#pragma unroll
        for (int i = 0; i < 4; ++i) {
            float4 t = *(const float4*)(qp + i * 32 + lane8 * 4);
            qv[g][i] = make_float4(t.x * SCALE, t.y * SCALE, t.z * SCALE, t.w * SCALE);
        }
    }

    constexpr int KIT = CHUNK / 8;
#pragma unroll 2
    for (int it = 0; it < KIT; ++it) {
        const int r  = it * 8 + grp;
        const int rl = (r < nvalid) ? r : nvalid - 1;    // branchless clamp
        const float* kb = kp[rl];
        float pd0 = 0.f, pd1 = 0.f, pd2 = 0.f, pd3 = 0.f;
#pragma unroll
        for (int j = 0; j < 4; ++j) {
            const float4 kv = *(const float4*)(kb + j * 32 + lane8 * 4);
            pd0 += kv.x * qv[0][j].x + kv.y * qv[0][j].y + kv.z * qv[0][j].z + kv.w * qv[0][j].w;
            pd1 += kv.x * qv[1][j].x + kv.y * qv[1][j].y + kv.z * qv[1][j].z + kv.w * qv[1][j].w;
            pd2 += kv.x * qv[2][j].x + kv.y * qv[2][j].y + kv.z * qv[2][j].z + kv.w * qv[2][j].w;
            pd3 += kv.x * qv[3][j].x + kv.y * qv[3][j].y + kv.z * qv[3][j].z + kv.w * qv[3][j].w;
        }
#pragma unroll
        for (int msk = 1; msk < 8; msk <<= 1) {
            pd0 += __shfl_xor(pd0, msk, 8);
            pd1 += __shfl_xor(pd1, msk, 8);
            pd2 += __shfl_xor(pd2, msk, 8);
            pd3 += __shfl_xor(pd3, msk, 8);
        }
        if (lane8 == 0) sc4[r] = make_float4(pd0, pd1, pd2, pd3);
    }

    // ---- softmax fully in-wave: lane l owns rows {l, l+64, ...}
    {
        constexpr int SR = (CHUNK + 63) / 64;
        float4 s[SR];
#pragma unroll
        for (int k2 = 0; k2 < SR; ++k2) {
            const int l = tid + k2 * 64;
            s[k2] = sc4[l];
            if (l >= nvalid) s[k2] = make_float4(-1e30f, -1e30f, -1e30f, -1e30f);
        }
        float m0 = s[0].x, m1 = s[0].y, m2 = s[0].z, m3 = s[0].w;
#pragma unroll
        for (int k2 = 1; k2 < SR; ++k2) {
            m0 = fmaxf(m0, s[k2].x); m1 = fmaxf(m1, s[k2].y);
            m2 = fmaxf(m2, s[k2].z); m3 = fmaxf(m3, s[k2].w);
        }
#pragma unroll
        for (int msk = 1; msk < 64; msk <<= 1) {
            m0 = fmaxf(m0, __shfl_xor(m0, msk));
            m1 = fmaxf(m1, __shfl_xor(m1, msk));
            m2 = fmaxf(m2, __shfl_xor(m2, msk));
            m3 = fmaxf(m3, __shfl_xor(m3, msk));
        }
        float l0 = 0.f, l1 = 0.f, l2 = 0.f, l3 = 0.f;
#pragma unroll
        for (int k2 = 0; k2 < SR; ++k2) {
            const float4 p = make_float4(__expf(s[k2].x - m0), __expf(s[k2].y - m1),
                                         __expf(s[k2].z - m2), __expf(s[k2].w - m3));
            l0 += p.x; l1 += p.y; l2 += p.z; l3 += p.w;
            sc4[tid + k2 * 64] = p;
        }
#pragma unroll
        for (int msk = 1; msk < 64; msk <<= 1) {
            l0 += __shfl_xor(l0, msk);
            l1 += __shfl_xor(l1, msk);
            l2 += __shfl_xor(l2, msk);
            l3 += __shfl_xor(l3, msk);
        }
        if (tid == 0) {
            *(float4*)&part_ml[pbase * 2 + 0] = make_float4(m0, l0, m1, l1);
            *(float4*)&part_ml[pbase * 2 + 4] = make_float4(m2, l2, m3, l3);
        }
    }

    // ---- PV: half = row parity, 32 d-lanes x float4; p=0 kills clamped rows
    {
        const int half = tid >> 5;
        const int dl   = tid & 31;
        float4 a0 = {0,0,0,0}, a1 = {0,0,0,0}, a2 = {0,0,0,0}, a3 = {0,0,0,0};
        constexpr int VJ = CHUNK / 2;
#pragma unroll 4
        for (int j = 0; j < VJ; ++j) {
            const int r  = 2 * j + half;
            const int rl = (r < nvalid) ? r : nvalid - 1;
            const float4 vv = *(const float4*)(vp[rl] + dl * 4);
            const float4 p4 = sc4[r];
            a0.x += p4.x * vv.x; a0.y += p4.x * vv.y; a0.z += p4.x * vv.z; a0.w += p4.x * vv.w;
            a1.x += p4.y * vv.x; a1.y += p4.y * vv.y; a1.z += p4.y * vv.z; a1.w += p4.y * vv.w;
            a2.x += p4.z * vv.x; a2.y += p4.z * vv.y; a2.z += p4.z * vv.z; a2.w += p4.z * vv.w;
            a3.x += p4.w * vv.x; a3.y += p4.w * vv.y; a3.z += p4.w * vv.z; a3.w += p4.w * vv.w;
        }
        // combine the two row-parities: xor-32 shuffle (both halves end full)
#pragma unroll
        for (int c = 0; c < 4; ++c) {
            ((float*)&a0)[c] += __shfl_xor(((float*)&a0)[c], 32);
            ((float*)&a1)[c] += __shfl_xor(((float*)&a1)[c], 32);
            ((float*)&a2)[c] += __shfl_xor(((float*)&a2)[c], 32);
            ((float*)&a3)[c] += __shfl_xor(((float*)&a3)[c], 32);
        }
        if (half == 0) {
            *(float4*)(part_o + (pbase + 0) * D + dl * 4) = a0;
            *(float4*)(part_o + (pbase + 1) * D + dl * 4) = a1;
        } else {
            *(float4*)(part_o + (pbase + 2) * D + dl * 4) = a2;
            *(float4*)(part_o + (pbase + 3) * D + dl * 4) = a3;
        }
    }
}

// Kernel 2: merge nsplit partials per (b, h, g) with log-sum-exp combine.
__global__ __launch_bounds__(128) void attn_reduce(
    const float* __restrict__ part_o,
    const float* __restrict__ part_ml,
    float* __restrict__ out,
    int nsplit)
{
    const int g = blockIdx.x & 3;
    const int h = (blockIdx.x >> 2) & 7;
    const int b = blockIdx.x >> 5;
    const int d = threadIdx.x;

    __shared__ float mlds[32], llds[32];
    const size_t base = (size_t)(b * HKV + h) * nsplit;

    for (int s = d; s < nsplit; s += 128) {
        mlds[s] = part_ml[((base + s) * G + g) * 2 + 0];
        llds[s] = part_ml[((base + s) * G + g) * 2 + 1];
    }
    __syncthreads();

    float M = -FLT_MAX;
    for (int s = 0; s < nsplit; ++s)
        if (llds[s] > 0.f) M = fmaxf(M, mlds[s]);

    float L = 0.f, acc = 0.f;
    for (int s = 0; s < nsplit; ++s) {
        const float l = llds[s];
        if (l > 0.f) {
            const float e = __expf(mlds[s] - M);
            L += l * e;
            acc += e * part_o[((base + s) * G + g) * D + d];
        }
    }
    out[((size_t)(b * H) + h * G + g) * D + d] = acc / (L > 0.f ? L : 1.f);
}

extern "C" void kernel_launch(void* const* d_in, const int* in_sizes, int n_in,
                              void* d_out, int out_size, void* d_ws, size_t ws_size,
                              hipStream_t stream) {
    const float* q  = (const float*)d_in[0];
    const float* k  = (const float*)d_in[1];
    const float* v  = (const float*)d_in[2];
    const float* kc = (const float*)d_in[3];
    const float* vc = (const float*)d_in[4];
    const int* slot_mapping = (const int*)d_in[5];
    const int* active_slots = (const int*)d_in[6];
    const int* context_lens = (const int*)d_in[7];
    float* out = (float*)d_out;

    const size_t perSplit = (size_t)B * HKV * (G * D + G * 2) * sizeof(float);
    int nsplit = 8;
    if (ws_size >= 32 * perSplit)      nsplit = 32;
    else if (ws_size >= 16 * perSplit) nsplit = 16;

    float* part_o  = (float*)d_ws;
    float* part_ml = part_o + (size_t)B * HKV * nsplit * G * D;

    if (nsplit == 32) {
        attn_partial<64><<<B * HKV * 32, 64, 0, stream>>>(
            q, k, v, kc, vc, slot_mapping, active_slots, context_lens, part_o, part_ml);
    } else if (nsplit == 16) {
        attn_partial<128><<<B * HKV * 16, 64, 0, stream>>>(
            q, k, v, kc, vc, slot_mapping, active_slots, context_lens, part_o, part_ml);
    } else {
        attn_partial<256><<<B * HKV * 8, 64, 0, stream>>>(
            q, k, v, kc, vc, slot_mapping, active_slots, context_lens, part_o, part_ml);
    }
    attn_reduce<<<B * HKV * G, 128, 0, stream>>>(part_o, part_ml, out, nsplit);
}